// Round 1
// baseline (156.755 us; speedup 1.0000x reference)
//
#include <hip/hip_runtime.h>

// GAT edge attention scores:
//   el[n,k] = sum_d feat_src[n,k,d] * attn_l[0,k,d]
//   er[n,k] = sum_d feat_dst[n,k,d] * attn_r[0,k,d]
//   out[e,k] = el[src_idx[e],k] + er[dst_idx[e],k]
// K=8, D=64 structural constants from the reference.

#define GAT_K 8
#define GAT_D 64

// One (n,k) row of 64 floats handled by a 16-lane group: lane i loads
// float4 at row*64 + i*4 from both feature tensors -> a full wave reads
// 2 x 1KB contiguous. attn tables are 2KB each, L1-resident.
__global__ void __launch_bounds__(256)
gat_score_kernel(const float* __restrict__ feat_src,
                 const float* __restrict__ feat_dst,
                 const float* __restrict__ attn_l,
                 const float* __restrict__ attn_r,
                 float* __restrict__ el,
                 float* __restrict__ er,
                 int num_rows /* = N*K */) {
    int tid  = blockIdx.x * blockDim.x + threadIdx.x;
    int row  = tid >> 4;      // (n*K + k)
    int lane = tid & 15;      // 0..15, lane*4 = starting d
    if (row >= num_rows) return;
    int k = row & (GAT_K - 1);

    const float4* fs = reinterpret_cast<const float4*>(feat_src) + row * (GAT_D / 4);
    const float4* fd = reinterpret_cast<const float4*>(feat_dst) + row * (GAT_D / 4);
    const float4* al = reinterpret_cast<const float4*>(attn_l)   + k   * (GAT_D / 4);
    const float4* ar = reinterpret_cast<const float4*>(attn_r)   + k   * (GAT_D / 4);

    float4 a = fs[lane];
    float4 b = fd[lane];
    float4 wl = al[lane];
    float4 wr = ar[lane];

    float sl = a.x * wl.x + a.y * wl.y + a.z * wl.z + a.w * wl.w;
    float sr = b.x * wr.x + b.y * wr.y + b.z * wr.z + b.w * wr.w;

    // reduce across the 16-lane group
    #pragma unroll
    for (int off = 8; off > 0; off >>= 1) {
        sl += __shfl_down(sl, off, 16);
        sr += __shfl_down(sr, off, 16);
    }
    if (lane == 0) {
        el[row] = sl;
        er[row] = sr;
    }
}

// One thread per edge: gather 8 floats (2 x float4) from el and er
// (6.4 MB total, L2/L3-resident) and write 32B contiguous output.
__global__ void __launch_bounds__(256)
gat_gather_kernel(const int* __restrict__ src_idx,
                  const int* __restrict__ dst_idx,
                  const float* __restrict__ el,
                  const float* __restrict__ er,
                  float* __restrict__ out,
                  int num_edges) {
    int e = blockIdx.x * blockDim.x + threadIdx.x;
    if (e >= num_edges) return;

    int s = src_idx[e];
    int d = dst_idx[e];

    const float4* pl = reinterpret_cast<const float4*>(el) + s * (GAT_K / 4);
    const float4* pr = reinterpret_cast<const float4*>(er) + d * (GAT_K / 4);

    float4 a0 = pl[0], a1 = pl[1];
    float4 b0 = pr[0], b1 = pr[1];

    float4 o0, o1;
    o0.x = a0.x + b0.x; o0.y = a0.y + b0.y; o0.z = a0.z + b0.z; o0.w = a0.w + b0.w;
    o1.x = a1.x + b1.x; o1.y = a1.y + b1.y; o1.z = a1.z + b1.z; o1.w = a1.w + b1.w;

    float4* po = reinterpret_cast<float4*>(out) + e * (GAT_K / 4);
    po[0] = o0;
    po[1] = o1;
}

extern "C" void kernel_launch(void* const* d_in, const int* in_sizes, int n_in,
                              void* d_out, int out_size, void* d_ws, size_t ws_size,
                              hipStream_t stream) {
    const float* feat_src = (const float*)d_in[0];
    const float* feat_dst = (const float*)d_in[1];
    const float* attn_l   = (const float*)d_in[2];
    const float* attn_r   = (const float*)d_in[3];
    const int*   src_idx  = (const int*)d_in[4];
    const int*   dst_idx  = (const int*)d_in[5];
    float* out = (float*)d_out;

    const int num_rows  = in_sizes[0] / GAT_D;   // N*K = 800000
    const int num_edges = in_sizes[4];           // E   = 3200000

    float* el = (float*)d_ws;                    // num_rows floats
    float* er = el + num_rows;                   // num_rows floats (6.4 MB total)

    // score kernel: 16 lanes per row
    {
        long long total_threads = (long long)num_rows * 16;
        int blocks = (int)((total_threads + 255) / 256);
        gat_score_kernel<<<blocks, 256, 0, stream>>>(feat_src, feat_dst,
                                                     attn_l, attn_r,
                                                     el, er, num_rows);
    }
    // gather kernel: 1 thread per edge
    {
        int blocks = (num_edges + 255) / 256;
        gat_gather_kernel<<<blocks, 256, 0, stream>>>(src_idx, dst_idx,
                                                      el, er, out, num_edges);
    }
}

// Round 2
// 153.015 us; speedup vs baseline: 1.0244x; 1.0244x over previous
//
#include <hip/hip_runtime.h>

// GAT edge attention scores:
//   el[n,k] = sum_d feat_src[n,k,d] * attn_l[0,k,d]
//   er[n,k] = sum_d feat_dst[n,k,d] * attn_r[0,k,d]
//   out[e,k] = el[src_idx[e],k] + er[dst_idx[e],k]
// K=8, D=64 structural constants from the reference.

#define GAT_K 8
#define GAT_D 64   // 16 float4 per row

typedef float f4 __attribute__((ext_vector_type(4)));

__device__ inline float dot4(f4 a, f4 b) {
    return a.x * b.x + a.y * b.y + a.z * b.z + a.w * b.w;
}

// 4 lanes per (n,k) row. Lane j owns bytes [j*64, j*64+64) of the 256B row:
// 4 independent float4 loads per tensor (8 loads in flight -> high MLP),
// then a 2-round width-4 xor-shuffle reduce (short dependency chain).
__global__ void __launch_bounds__(256)
gat_score_kernel(const f4* __restrict__ fs4,
                 const f4* __restrict__ fd4,
                 const f4* __restrict__ al4,
                 const f4* __restrict__ ar4,
                 float* __restrict__ el,
                 float* __restrict__ er,
                 int num_rows /* = N*K */) {
    int tid = blockIdx.x * blockDim.x + threadIdx.x;
    int row = tid >> 2;       // (n*K + k)
    int j   = tid & 3;        // quarter-row index
    if (row >= num_rows) return;
    int k = row & (GAT_K - 1);

    const f4* fsp = fs4 + row * (GAT_D / 4) + j * 4;
    const f4* fdp = fd4 + row * (GAT_D / 4) + j * 4;
    const f4* alp = al4 + k   * (GAT_D / 4) + j * 4;
    const f4* arp = ar4 + k   * (GAT_D / 4) + j * 4;

    // 8 independent feature loads issued before any use
    f4 a0 = fsp[0], a1 = fsp[1], a2 = fsp[2], a3 = fsp[3];
    f4 b0 = fdp[0], b1 = fdp[1], b2 = fdp[2], b3 = fdp[3];
    // attn tables: 2KB each, L1-resident broadcast
    f4 l0 = alp[0], l1 = alp[1], l2 = alp[2], l3 = alp[3];
    f4 r0 = arp[0], r1 = arp[1], r2 = arp[2], r3 = arp[3];

    float sl = dot4(a0, l0) + dot4(a1, l1) + dot4(a2, l2) + dot4(a3, l3);
    float sr = dot4(b0, r0) + dot4(b1, r1) + dot4(b2, r2) + dot4(b3, r3);

    // 2-round reduce across the 4-lane group (independent chains for sl/sr)
    sl += __shfl_xor(sl, 1, 4);
    sr += __shfl_xor(sr, 1, 4);
    sl += __shfl_xor(sl, 2, 4);
    sr += __shfl_xor(sr, 2, 4);

    if (j == 0) {
        el[row] = sl;
        er[row] = sr;
    }
}

// One thread per edge: gather 2x32B from el/er (L2/L3-resident, 6.4MB),
// write 32B contiguous output with nontemporal stores (write-once stream,
// keeps L2 capacity for the el/er gathers).
__global__ void __launch_bounds__(256)
gat_gather_kernel(const int* __restrict__ src_idx,
                  const int* __restrict__ dst_idx,
                  const f4* __restrict__ el4,
                  const f4* __restrict__ er4,
                  f4* __restrict__ out4,
                  int num_edges) {
    int e = blockIdx.x * blockDim.x + threadIdx.x;
    if (e >= num_edges) return;

    int s = src_idx[e];
    int d = dst_idx[e];

    f4 a0 = el4[s * 2 + 0];
    f4 a1 = el4[s * 2 + 1];
    f4 b0 = er4[d * 2 + 0];
    f4 b1 = er4[d * 2 + 1];

    f4 o0 = a0 + b0;
    f4 o1 = a1 + b1;

    __builtin_nontemporal_store(o0, out4 + e * 2 + 0);
    __builtin_nontemporal_store(o1, out4 + e * 2 + 1);
}

extern "C" void kernel_launch(void* const* d_in, const int* in_sizes, int n_in,
                              void* d_out, int out_size, void* d_ws, size_t ws_size,
                              hipStream_t stream) {
    const f4* feat_src = (const f4*)d_in[0];
    const f4* feat_dst = (const f4*)d_in[1];
    const f4* attn_l   = (const f4*)d_in[2];
    const f4* attn_r   = (const f4*)d_in[3];
    const int* src_idx = (const int*)d_in[4];
    const int* dst_idx = (const int*)d_in[5];

    const int num_rows  = in_sizes[0] / GAT_D;   // N*K = 800000
    const int num_edges = in_sizes[4];           // E   = 3200000

    float* el = (float*)d_ws;                    // num_rows floats
    float* er = el + num_rows;                   // num_rows floats (6.4MB total)

    // score kernel: 4 lanes per row
    {
        long long total_threads = (long long)num_rows * 4;
        int blocks = (int)((total_threads + 255) / 256);
        gat_score_kernel<<<blocks, 256, 0, stream>>>(feat_src, feat_dst,
                                                     attn_l, attn_r,
                                                     el, er, num_rows);
    }
    // gather kernel: 1 thread per edge
    {
        int blocks = (num_edges + 255) / 256;
        gat_gather_kernel<<<blocks, 256, 0, stream>>>(src_idx, dst_idx,
                                                      (const f4*)el, (const f4*)er,
                                                      (f4*)d_out, num_edges);
    }
}